// Round 1
// baseline (5924.281 us; speedup 1.0000x reference)
//
#include <hip/hip_runtime.h>
#include <cstdio>

#define BB 4
#define C 64
#define HH 192
#define WW 192
#define NPIX (HH*WW)            /* 36864 */
#define ST (BB*C*NPIX)          /* 9437184 floats per tensor */

__device__ __forceinline__ float gelu_f(float v) {
    return 0.5f * v * (1.0f + erff(v * 0.70710678118654752440f));
}

// ---------------------------------------------------------------------------
// Generic 1x1 conv over NCHW: out[b,o,n] = sum_c W[o,c]*in[b,c,n] (+ ...)
// grid = (NPIX/256, B), block = 256. Weights indexed wave-uniformly -> s_load.
// ---------------------------------------------------------------------------
template<bool TWO_IN, bool TWO_OUT, bool PERB, bool DO_GELU>
__global__ __launch_bounds__(256) void k_conv(
    const float* __restrict__ in1, const float* __restrict__ in2,
    const float* __restrict__ W1, const float* __restrict__ W2,
    const float* __restrict__ bias1, const float* __restrict__ bias2,
    const float* __restrict__ res, float* __restrict__ out1,
    float* __restrict__ out2, int ldw)
{
    const int n = blockIdx.x * 256 + threadIdx.x;
    const int b = blockIdx.y;
    const int base = b * (C * NPIX) + n;
    float xv[C];
#pragma unroll
    for (int c = 0; c < C; ++c) xv[c] = in1[base + c * NPIX];
    float yv[TWO_IN ? C : 1];
    if (TWO_IN) {
#pragma unroll
        for (int c = 0; c < C; ++c) yv[c] = in2[base + c * NPIX];
    }
    const float* w1 = W1 + (PERB ? b * C * C : 0);
    for (int o = 0; o < C; ++o) {
        const float* wr = w1 + o * ldw;
        float a0 = 0.f, a1 = 0.f, a2 = 0.f, a3 = 0.f;
#pragma unroll
        for (int c = 0; c < C; c += 4) {
            a0 += wr[c+0] * xv[c+0];
            a1 += wr[c+1] * xv[c+1];
            a2 += wr[c+2] * xv[c+2];
            a3 += wr[c+3] * xv[c+3];
        }
        if (TWO_IN) {
            const float* wr2 = W2 + o * ldw;
#pragma unroll
            for (int c = 0; c < C; c += 4) {
                a0 += wr2[c+0] * yv[c+0];
                a1 += wr2[c+1] * yv[c+1];
                a2 += wr2[c+2] * yv[c+2];
                a3 += wr2[c+3] * yv[c+3];
            }
        }
        float acc = (a0 + a1) + (a2 + a3);
        if (bias1) acc += bias1[o];
        if (TWO_IN) { if (bias2) acc += bias2[o]; }
        const int ob = base + o * NPIX;
        if (res) acc += res[ob];
        if (DO_GELU) acc = gelu_f(acc);
        out1[ob] = acc;
        if (TWO_OUT) {
            const float* wr2 = W2 + o * ldw;
            float c0 = 0.f, c1 = 0.f, c2_ = 0.f, c3 = 0.f;
#pragma unroll
            for (int c = 0; c < C; c += 4) {
                c0  += wr2[c+0] * xv[c+0];
                c1  += wr2[c+1] * xv[c+1];
                c2_ += wr2[c+2] * xv[c+2];
                c3  += wr2[c+3] * xv[c+3];
            }
            out2[ob] = (c0 + c1) + (c2_ + c3);
        }
    }
}

// ---------------------------------------------------------------------------
// Depthwise 3x3 (pad 1) + bias + GELU.  grid = (H, B*C), block = 192 (=W).
// ---------------------------------------------------------------------------
__global__ __launch_bounds__(192) void k_dw(
    const float* __restrict__ t0, const float* __restrict__ w,
    const float* __restrict__ bias, float* __restrict__ g)
{
    const int x = threadIdx.x;        // 0..191
    const int y = blockIdx.x;         // 0..191
    const int bc = blockIdx.y;        // 0..255
    const int c = bc & 63;
    const float* img = t0 + bc * NPIX;
    const float* wc = w + c * 9;
    float acc = bias[c];
#pragma unroll
    for (int dy = -1; dy <= 1; ++dy) {
        const int yy = y + dy;
        if (yy < 0 || yy > 191) continue;
#pragma unroll
        for (int dx = -1; dx <= 1; ++dx) {
            const int xx = x + dx;
            if (xx < 0 || xx > 191) continue;
            acc += img[yy*WW + xx] * wc[(dy+1)*3 + (dx+1)];
        }
    }
    g[bc*NPIX + y*WW + x] = gelu_f(acc);
}

// ---------------------------------------------------------------------------
// Per-batch Gram G1 = X1 * X1^T: partial per 256-pixel chunk.
// grid = (144, B), block = 256. dyn LDS = 256*68*4 = 69632 B.
// ---------------------------------------------------------------------------
__global__ __launch_bounds__(256) void k_gram_part(
    const float* __restrict__ x1p, float* __restrict__ part)
{
    extern __shared__ float lt[];     // [256][68]
    const int chunk = blockIdx.x, b = blockIdx.y, t = threadIdx.x;
    const int gbase = b * (C*NPIX) + chunk * 256;
    for (int idx = t; idx < C*256; idx += 256) {
        const int c = idx >> 8, n = idx & 255;
        lt[n*68 + c] = x1p[gbase + c*NPIX + n];
    }
    __syncthreads();
    const int ti = t & 15, tj = t >> 4;
    float acc[4][4];
#pragma unroll
    for (int r = 0; r < 4; ++r)
#pragma unroll
        for (int s = 0; s < 4; ++s) acc[r][s] = 0.f;
    for (int n = 0; n < 256; ++n) {
        const float4 av = *reinterpret_cast<const float4*>(&lt[n*68 + 4*ti]);
        const float4 bv = *reinterpret_cast<const float4*>(&lt[n*68 + 4*tj]);
        const float ar[4] = {av.x, av.y, av.z, av.w};
        const float br[4] = {bv.x, bv.y, bv.z, bv.w};
#pragma unroll
        for (int r = 0; r < 4; ++r)
#pragma unroll
            for (int s = 0; s < 4; ++s) acc[r][s] += ar[r] * br[s];
    }
    float* pb = part + (b*144 + chunk)*4096;
#pragma unroll
    for (int r = 0; r < 4; ++r)
#pragma unroll
        for (int s = 0; s < 4; ++s) pb[(4*ti+r)*64 + (4*tj+s)] = acc[r][s];
}

__global__ __launch_bounds__(256) void k_gram_reduce(
    const float* __restrict__ part, float* __restrict__ G1)
{
    const int flat = blockIdx.x*256 + threadIdx.x;   // < 16384
    const int b = flat >> 12, ij = flat & 4095;
    float s = 0.f;
    for (int ch = 0; ch < 144; ++ch) s += part[(b*144+ch)*4096 + ij];
    G1[flat] = s;
}

// ---------------------------------------------------------------------------
// Channel-attention collapse: per batch, M2 = Wp * blockdiag(attn) * Wv where
// attn = softmax_d( (Wq G1 Wk^T)[block] * temp / (|q| |k|) ).
// grid = B, block = 256, dyn LDS = 18560*4 = 74240 B.
// ---------------------------------------------------------------------------
__global__ __launch_bounds__(256) void k_attn_small(
    const float* __restrict__ G1a, const float* __restrict__ Wq,
    const float* __restrict__ Wk, const float* __restrict__ Wv,
    const float* __restrict__ Wp, const float* __restrict__ temp,
    float* __restrict__ M2)
{
    extern __shared__ float sm[];
    float* g1 = sm;            // 4096 (Gram, later reused for M_av)
    float* wa = sm + 4096;     // 4096 (Wq, later Wv)
    float* wb = sm + 8192;     // 4096 (Wk, later Wp)
    float* u  = sm + 12288;    // 4096 (Wq @ G1)
    float* at = sm + 16384;    // 2048 (attn, 2 groups of 32x32)
    float* nq = sm + 18432;    // 64
    float* nk = sm + 18496;    // 64
    const int b = blockIdx.x, t = threadIdx.x;
    const float* G = G1a + b*4096;
    for (int i = t; i < 4096; i += 256) { g1[i] = G[i]; wa[i] = Wq[i]; wb[i] = Wk[i]; }
    __syncthreads();
    {   // u = Wq @ G1
        const int r = t >> 2, q4 = t & 3;
        for (int cc = q4*16; cc < q4*16 + 16; ++cc) {
            float s = 0.f;
            for (int k = 0; k < 64; ++k) s += wa[r*64+k] * g1[k*64+cc];
            u[r*64+cc] = s;
        }
    }
    __syncthreads();
    {   // nk[d] = sqrt( Wk_d . (G1 @ Wk_d) ) via 4 lanes per d
        const int d = t >> 2, kq = t & 3;
        float p = 0.f;
        for (int k = kq*16; k < kq*16 + 16; ++k) {
            float tk = 0.f;
            for (int c2 = 0; c2 < 64; ++c2) tk += g1[k*64+c2] * wb[d*64+c2];
            p += wb[d*64+k] * tk;
        }
        p += __shfl_xor(p, 1);
        p += __shfl_xor(p, 2);
        if (kq == 0) nk[d] = sqrtf(fmaxf(p, 0.f));
    }
    if (t < 64) {   // nq[r] = sqrt( (U Wq^T)[r,r] )
        float s = 0.f;
        for (int c2 = 0; c2 < 64; ++c2) s += u[t*64+c2] * wa[t*64+c2];
        nq[t] = sqrtf(fmaxf(s, 0.f));
    }
    __syncthreads();
    if (t < 64) {   // logits row t (within its 32-wide group) + softmax
        const int gI = t >> 5;
        const float tg = temp[gI];
        const float dq = fmaxf(nq[t], 1e-12f);
        float row[32];
        float mx = -1e30f;
#pragma unroll
        for (int d2 = 0; d2 < 32; ++d2) {
            const int dd = gI*32 + d2;
            float s = 0.f;
            for (int c2 = 0; c2 < 64; ++c2) s += u[t*64+c2] * wb[dd*64+c2];
            s = s * tg / (dq * fmaxf(nk[dd], 1e-12f));
            row[d2] = s; mx = fmaxf(mx, s);
        }
        float se = 0.f;
#pragma unroll
        for (int d2 = 0; d2 < 32; ++d2) { row[d2] = __expf(row[d2]-mx); se += row[d2]; }
        const float inv = 1.f / se;
#pragma unroll
        for (int d2 = 0; d2 < 32; ++d2) at[t*32+d2] = row[d2]*inv;
    }
    __syncthreads();
    for (int i = t; i < 4096; i += 256) { wa[i] = Wv[i]; wb[i] = Wp[i]; }
    __syncthreads();
    {   // M_av = blockdiag(attn) @ Wv -> into g1 (Gram no longer needed)
        const int m = t >> 2, q4 = t & 3, gI = m >> 5;
        for (int e = q4*16; e < q4*16 + 16; ++e) {
            float s = 0.f;
#pragma unroll
            for (int d2 = 0; d2 < 32; ++d2) s += at[m*32+d2] * wa[(gI*32+d2)*64 + e];
            g1[m*64+e] = s;
        }
    }
    __syncthreads();
    {   // M2 = Wp @ M_av
        const int o = t >> 2, q4 = t & 3;
        for (int e = q4*16; e < q4*16 + 16; ++e) {
            float s = 0.f;
            for (int m = 0; m < 64; ++m) s += wb[o*64+m] * g1[m*64+e];
            M2[b*4096 + o*64+e] = s;
        }
    }
}

// ---------------------------------------------------------------------------
// Row attention (also used for columns on HW-transposed tensors).
// grid = (192, B), block = 192 (thread i owns score row i). No barriers needed:
// each thread uses only its own LDS row. dyn LDS = 192*193*4 = 148224 B.
// OUT[c,line,i] = gamma * sum_j V[c,line,j]*softmax_j(Q[:,line,i].K[:,line,j]) + X
// ---------------------------------------------------------------------------
__global__ __launch_bounds__(192) void k_rowattn(
    const float* __restrict__ Q, const float* __restrict__ K,
    const float* __restrict__ V, const float* __restrict__ X,
    float* __restrict__ OUT, const float* __restrict__ gammap)
{
    extern __shared__ float S[];      // [192][193]
    const int i = threadIdx.x;
    const int h = blockIdx.x, b = blockIdx.y;
    const int base = b * (C*NPIX) + h * WW;    // + c*NPIX + j
    float q[C];
#pragma unroll
    for (int c = 0; c < C; ++c) q[c] = Q[base + c*NPIX + i];
    for (int j = 0; j < WW; ++j) {
        float a0 = 0.f, a1 = 0.f, a2 = 0.f, a3 = 0.f;
#pragma unroll
        for (int c = 0; c < C; c += 4) {
            a0 += q[c+0] * K[base + (c+0)*NPIX + j];
            a1 += q[c+1] * K[base + (c+1)*NPIX + j];
            a2 += q[c+2] * K[base + (c+2)*NPIX + j];
            a3 += q[c+3] * K[base + (c+3)*NPIX + j];
        }
        S[i*193 + j] = (a0 + a1) + (a2 + a3);
    }
    float mx = -1e30f;
    for (int j = 0; j < WW; ++j) mx = fmaxf(mx, S[i*193+j]);
    float se = 0.f;
    for (int j = 0; j < WW; ++j) { float e = __expf(S[i*193+j] - mx); S[i*193+j] = e; se += e; }
    float acc[C];
#pragma unroll
    for (int c = 0; c < C; ++c) acc[c] = 0.f;
    for (int j = 0; j < WW; ++j) {
        const float a = S[i*193+j];
#pragma unroll
        for (int c = 0; c < C; ++c) acc[c] += a * V[base + c*NPIX + j];
    }
    const float inv = gammap[0] / se;
#pragma unroll
    for (int c = 0; c < C; ++c) {
        const int idx = base + c*NPIX + i;
        OUT[idx] = acc[c] * inv + X[idx];
    }
}

// ---------------------------------------------------------------------------
// HW transpose per image: out[img][x][y] = in[img][y][x]. grid (6,6,B*C).
// ---------------------------------------------------------------------------
__global__ __launch_bounds__(256) void k_transpose(
    const float* __restrict__ in, float* __restrict__ out)
{
    __shared__ float tile[32][33];
    const int tx = threadIdx.x & 31, ty = threadIdx.x >> 5;  // 32x8
    const int x0 = blockIdx.x*32, y0 = blockIdx.y*32;
    const float* img = in + blockIdx.z * NPIX;
    float* og = out + blockIdx.z * NPIX;
#pragma unroll
    for (int r = ty; r < 32; r += 8) tile[r][tx] = img[(y0+r)*WW + x0+tx];
    __syncthreads();
#pragma unroll
    for (int r = ty; r < 32; r += 8) og[(x0+r)*WW + (y0+tx)] = tile[tx][r];
}

// ---------------------------------------------------------------------------
extern "C" void kernel_launch(void* const* d_in, const int* in_sizes, int n_in,
                              void* d_out, int out_size, void* d_ws, size_t ws_size,
                              hipStream_t stream) {
    const float* x       = (const float*)d_in[0];
    const float* pw_w    = (const float*)d_in[1];
    const float* dw_w    = (const float*)d_in[2];
    const float* dw_b    = (const float*)d_in[3];
    const float* conv2_w = (const float*)d_in[4];
    const float* conv2_b = (const float*)d_in[5];
    const float* conv0_w = (const float*)d_in[6];
    const float* conv0_b = (const float*)d_in[7];
    const float* attq    = (const float*)d_in[8];
    const float* attk    = (const float*)d_in[9];
    const float* attv    = (const float*)d_in[10];
    const float* attp    = (const float*)d_in[11];
    const float* temp    = (const float*)d_in[12];
    const float* rq      = (const float*)d_in[13];
    const float* rk      = (const float*)d_in[14];
    const float* rv      = (const float*)d_in[15];
    const float* rg      = (const float*)d_in[16];
    const float* cq      = (const float*)d_in[17];
    const float* ck      = (const float*)d_in[18];
    const float* cv      = (const float*)d_in[19];
    const float* cg      = (const float*)d_in[20];
    const float* fw      = (const float*)d_in[21];
    const float* fb      = (const float*)d_in[22];

    float* ws = (float*)d_ws;
    float* b0 = ws;               // t0 -> out1
    float* b1 = ws + (size_t)ST;  // g -> Qr -> x1t -> out3t (in-place)
    float* b2 = ws + 2*(size_t)ST;// x1 -> Kc -> tmp (final accum)
    float* b3 = ws + 3*(size_t)ST;// Kr -> out1t -> Qc -> out3
    float* b4 = ws + 4*(size_t)ST;// Vr -> Vc
    float* b5 = ws + 5*(size_t)ST;// out2
    float* partials = ws + 6*(size_t)ST;          // 576*4096
    float* G1 = partials + 576*4096;              // 4*4096
    float* M2 = G1 + 16384;                       // 4*4096

    const size_t need = ((size_t)6*ST + 576*4096 + 16384 + 16384) * sizeof(float);
    if (ws_size < need) {
        fprintf(stderr, "kernel_launch: ws_size %zu < needed %zu\n", ws_size, need);
        return;
    }

    (void)hipFuncSetAttribute((const void*)k_gram_part,
        hipFuncAttributeMaxDynamicSharedMemorySize, 69632);
    (void)hipFuncSetAttribute((const void*)k_attn_small,
        hipFuncAttributeMaxDynamicSharedMemorySize, 74240);
    (void)hipFuncSetAttribute((const void*)k_rowattn,
        hipFuncAttributeMaxDynamicSharedMemorySize, 148224);

    const dim3 blk256(256), blk192(192);
    const dim3 gconv(NPIX/256, BB);   // (144, 4)

    // 1) t0 = pw_w @ x
    k_conv<false,false,false,false><<<gconv, blk256, 0, stream>>>(
        x, nullptr, pw_w, nullptr, nullptr, nullptr, nullptr, b0, nullptr, 64);
    // 2) g = gelu(dw3x3(t0) + dw_b)
    k_dw<<<dim3(HH, BB*C), blk192, 0, stream>>>(b0, dw_w, dw_b, b1);
    // 3) x1 = conv2@g + conv2_b + conv0@x + conv0_b
    k_conv<true,false,false,false><<<gconv, blk256, 0, stream>>>(
        b1, x, conv2_w, conv0_w, conv2_b, conv0_b, nullptr, b2, nullptr, 64);
    // 4) G1[b] = x1 x1^T
    k_gram_part<<<gconv, blk256, 69632, stream>>>(b2, partials);
    k_gram_reduce<<<dim3(64), blk256, 0, stream>>>(partials, G1);
    // 5) M2[b] = Wp * blockdiag(attn) * Wv
    k_attn_small<<<dim3(BB), blk256, 74240, stream>>>(G1, attq, attk, attv, attp, temp, M2);
    // 6) out1 = M2[b] @ x1
    k_conv<false,false,true,false><<<gconv, blk256, 0, stream>>>(
        b2, nullptr, M2, nullptr, nullptr, nullptr, nullptr, b0, nullptr, 64);
    // 7) Qr, Kr from x1
    k_conv<false,true,false,false><<<gconv, blk256, 0, stream>>>(
        b2, nullptr, rq, rk, nullptr, nullptr, nullptr, b1, b3, 64);
    // 8) Vr from out1
    k_conv<false,false,false,false><<<gconv, blk256, 0, stream>>>(
        b0, nullptr, rv, nullptr, nullptr, nullptr, nullptr, b4, nullptr, 64);
    // 9) out2 = row_gamma * rowattn + x1
    k_rowattn<<<dim3(HH, BB), blk192, 148224, stream>>>(b1, b3, b4, b2, b5, rg);
    // 10) x1t, out1t
    k_transpose<<<dim3(6,6,BB*C), blk256, 0, stream>>>(b2, b1);
    k_transpose<<<dim3(6,6,BB*C), blk256, 0, stream>>>(b0, b3);
    // 11) Vc from out1t
    k_conv<false,false,false,false><<<gconv, blk256, 0, stream>>>(
        b3, nullptr, cv, nullptr, nullptr, nullptr, nullptr, b4, nullptr, 64);
    // 12) Qc, Kc from x1t
    k_conv<false,true,false,false><<<gconv, blk256, 0, stream>>>(
        b1, nullptr, cq, ck, nullptr, nullptr, nullptr, b3, b2, 64);
    // 13) out3t = col_gamma * colattn + x1t  (in-place over x1t: per-element
    //     residual read happens in the writing thread right before the store)
    k_rowattn<<<dim3(WW, BB), blk192, 148224, stream>>>(b3, b2, b4, b1, b1, cg);
    // 14) out3 = transpose(out3t)
    k_transpose<<<dim3(6,6,BB*C), blk256, 0, stream>>>(b1, b3);
    // 15) final fuse conv in 3 passes over the 192-channel concat
    k_conv<false,false,false,false><<<gconv, blk256, 0, stream>>>(
        b0, nullptr, fw + 0, nullptr, fb, nullptr, nullptr, b2, nullptr, 192);
    k_conv<false,false,false,false><<<gconv, blk256, 0, stream>>>(
        b5, nullptr, fw + 64, nullptr, nullptr, nullptr, b2, b2, nullptr, 192);
    k_conv<false,false,false,true><<<gconv, blk256, 0, stream>>>(
        b3, nullptr, fw + 128, nullptr, nullptr, nullptr, b2, (float*)d_out, nullptr, 192);
}

// Round 3
// 1343.538 us; speedup vs baseline: 4.4095x; 4.4095x over previous
//
#include <hip/hip_runtime.h>
#include <cstdio>

#define BB 4
#define C 64
#define HH 192
#define WW 192
#define NPIX (HH*WW)            /* 36864 */
#define ST (BB*C*NPIX)          /* 9437184 floats per tensor */
#define LINE_ELEMS (HH*WW)      /* per-line S matrix: 192*192 */

__device__ __forceinline__ float gelu_f(float v) {
    return 0.5f * v * (1.0f + erff(v * 0.70710678118654752440f));
}

// ---------------------------------------------------------------------------
// Generic 1x1 conv over NCHW: out[b,o,n] = W1@in1 (+ W2@in2) (+bias1)(+bias2)
// (+res)(gelu). grid = (NPIX/256, B), block = 256. out1 never aliases inputs.
// ---------------------------------------------------------------------------
template<bool TWO_IN, bool PERB, bool DO_GELU>
__global__ __launch_bounds__(256) void k_conv(
    const float* __restrict__ in1, const float* __restrict__ in2,
    const float* __restrict__ W1, const float* __restrict__ W2,
    const float* __restrict__ bias1, const float* __restrict__ bias2,
    const float* __restrict__ res, float* __restrict__ out1,
    int ldw1, int ldw2)
{
    const int n = blockIdx.x * 256 + threadIdx.x;
    const int b = blockIdx.y;
    const int base = b * (C * NPIX) + n;
    float xv[C];
#pragma unroll
    for (int c = 0; c < C; ++c) xv[c] = in1[base + c * NPIX];
    float yv[TWO_IN ? C : 1];
    if (TWO_IN) {
#pragma unroll
        for (int c = 0; c < C; ++c) yv[c] = in2[base + c * NPIX];
    }
    const float* w1 = W1 + (PERB ? b * C * C : 0);
    for (int o = 0; o < C; ++o) {
        const float* wr = w1 + o * ldw1;
        float a0 = 0.f, a1 = 0.f, a2 = 0.f, a3 = 0.f;
#pragma unroll
        for (int c = 0; c < C; c += 4) {
            a0 += wr[c+0] * xv[c+0];
            a1 += wr[c+1] * xv[c+1];
            a2 += wr[c+2] * xv[c+2];
            a3 += wr[c+3] * xv[c+3];
        }
        if (TWO_IN) {
            const float* wr2 = W2 + o * ldw2;
#pragma unroll
            for (int c = 0; c < C; c += 4) {
                a0 += wr2[c+0] * yv[c+0];
                a1 += wr2[c+1] * yv[c+1];
                a2 += wr2[c+2] * yv[c+2];
                a3 += wr2[c+3] * yv[c+3];
            }
        }
        float acc = (a0 + a1) + (a2 + a3);
        if (bias1) acc += bias1[o];
        if (bias2) acc += bias2[o];
        const int ob = base + o * NPIX;
        if (res) acc += res[ob];
        if (DO_GELU) acc = gelu_f(acc);
        out1[ob] = acc;
    }
}

// ---------------------------------------------------------------------------
// Depthwise 3x3 (pad 1) + bias + GELU.  grid = (H, B*C), block = 192 (=W).
// ---------------------------------------------------------------------------
__global__ __launch_bounds__(192) void k_dw(
    const float* __restrict__ t0, const float* __restrict__ w,
    const float* __restrict__ bias, float* __restrict__ g)
{
    const int x = threadIdx.x;
    const int y = blockIdx.x;
    const int bc = blockIdx.y;
    const int c = bc & 63;
    const float* img = t0 + bc * NPIX;
    const float* wc = w + c * 9;
    float acc = bias[c];
#pragma unroll
    for (int dy = -1; dy <= 1; ++dy) {
        const int yy = y + dy;
        if (yy < 0 || yy > 191) continue;
#pragma unroll
        for (int dx = -1; dx <= 1; ++dx) {
            const int xx = x + dx;
            if (xx < 0 || xx > 191) continue;
            acc += img[yy*WW + xx] * wc[(dy+1)*3 + (dx+1)];
        }
    }
    g[bc*NPIX + y*WW + x] = gelu_f(acc);
}

// ---------------------------------------------------------------------------
// Per-batch Gram G1 = X1 * X1^T: partial per 256-pixel chunk.
// ---------------------------------------------------------------------------
__global__ __launch_bounds__(256) void k_gram_part(
    const float* __restrict__ x1p, float* __restrict__ part)
{
    extern __shared__ float lt[];     // [256][68]
    const int chunk = blockIdx.x, b = blockIdx.y, t = threadIdx.x;
    const int gbase = b * (C*NPIX) + chunk * 256;
    for (int idx = t; idx < C*256; idx += 256) {
        const int c = idx >> 8, n = idx & 255;
        lt[n*68 + c] = x1p[gbase + c*NPIX + n];
    }
    __syncthreads();
    const int ti = t & 15, tj = t >> 4;
    float acc[4][4];
#pragma unroll
    for (int r = 0; r < 4; ++r)
#pragma unroll
        for (int s = 0; s < 4; ++s) acc[r][s] = 0.f;
    for (int n = 0; n < 256; ++n) {
        const float4 av = *reinterpret_cast<const float4*>(&lt[n*68 + 4*ti]);
        const float4 bv = *reinterpret_cast<const float4*>(&lt[n*68 + 4*tj]);
        const float ar[4] = {av.x, av.y, av.z, av.w};
        const float br[4] = {bv.x, bv.y, bv.z, bv.w};
#pragma unroll
        for (int r = 0; r < 4; ++r)
#pragma unroll
            for (int s = 0; s < 4; ++s) acc[r][s] += ar[r] * br[s];
    }
    float* pb = part + (b*144 + chunk)*4096;
#pragma unroll
    for (int r = 0; r < 4; ++r)
#pragma unroll
        for (int s = 0; s < 4; ++s) pb[(4*ti+r)*64 + (4*tj+s)] = acc[r][s];
}

__global__ __launch_bounds__(256) void k_gram_reduce(
    const float* __restrict__ part, float* __restrict__ G1)
{
    const int flat = blockIdx.x*256 + threadIdx.x;   // < 16384
    const int b = flat >> 12, ij = flat & 4095;
    float s = 0.f;
    for (int ch = 0; ch < 144; ++ch) s += part[(b*144+ch)*4096 + ij];
    G1[flat] = s;
}

// ---------------------------------------------------------------------------
// Channel-attention collapse: per batch, M2 = Wp * blockdiag(attn) * Wv.
// ---------------------------------------------------------------------------
__global__ __launch_bounds__(256) void k_attn_small(
    const float* __restrict__ G1a, const float* __restrict__ Wq,
    const float* __restrict__ Wk, const float* __restrict__ Wv,
    const float* __restrict__ Wp, const float* __restrict__ temp,
    float* __restrict__ M2)
{
    extern __shared__ float sm[];
    float* g1 = sm;
    float* wa = sm + 4096;
    float* wb = sm + 8192;
    float* u  = sm + 12288;
    float* at = sm + 16384;
    float* nq = sm + 18432;
    float* nk = sm + 18496;
    const int b = blockIdx.x, t = threadIdx.x;
    const float* G = G1a + b*4096;
    for (int i = t; i < 4096; i += 256) { g1[i] = G[i]; wa[i] = Wq[i]; wb[i] = Wk[i]; }
    __syncthreads();
    {
        const int r = t >> 2, q4 = t & 3;
        for (int cc = q4*16; cc < q4*16 + 16; ++cc) {
            float s = 0.f;
            for (int k = 0; k < 64; ++k) s += wa[r*64+k] * g1[k*64+cc];
            u[r*64+cc] = s;
        }
    }
    __syncthreads();
    {
        const int d = t >> 2, kq = t & 3;
        float p = 0.f;
        for (int k = kq*16; k < kq*16 + 16; ++k) {
            float tk = 0.f;
            for (int c2 = 0; c2 < 64; ++c2) tk += g1[k*64+c2] * wb[d*64+c2];
            p += wb[d*64+k] * tk;
        }
        p += __shfl_xor(p, 1);
        p += __shfl_xor(p, 2);
        if (kq == 0) nk[d] = sqrtf(fmaxf(p, 0.f));
    }
    if (t < 64) {
        float s = 0.f;
        for (int c2 = 0; c2 < 64; ++c2) s += u[t*64+c2] * wa[t*64+c2];
        nq[t] = sqrtf(fmaxf(s, 0.f));
    }
    __syncthreads();
    if (t < 64) {
        const int gI = t >> 5;
        const float tg = temp[gI];
        const float dq = fmaxf(nq[t], 1e-12f);
        float row[32];
        float mx = -1e30f;
#pragma unroll
        for (int d2 = 0; d2 < 32; ++d2) {
            const int dd = gI*32 + d2;
            float s = 0.f;
            for (int c2 = 0; c2 < 64; ++c2) s += u[t*64+c2] * wb[dd*64+c2];
            s = s * tg / (dq * fmaxf(nk[dd], 1e-12f));
            row[d2] = s; mx = fmaxf(mx, s);
        }
        float se = 0.f;
#pragma unroll
        for (int d2 = 0; d2 < 32; ++d2) { row[d2] = __expf(row[d2]-mx); se += row[d2]; }
        const float inv = 1.f / se;
#pragma unroll
        for (int d2 = 0; d2 < 32; ++d2) at[t*32+d2] = row[d2]*inv;
    }
    __syncthreads();
    for (int i = t; i < 4096; i += 256) { wa[i] = Wv[i]; wb[i] = Wp[i]; }
    __syncthreads();
    {
        const int m = t >> 2, q4 = t & 3, gI = m >> 5;
        for (int e = q4*16; e < q4*16 + 16; ++e) {
            float s = 0.f;
#pragma unroll
            for (int d2 = 0; d2 < 32; ++d2) s += at[m*32+d2] * wa[(gI*32+d2)*64 + e];
            g1[m*64+e] = s;
        }
    }
    __syncthreads();
    {
        const int o = t >> 2, q4 = t & 3;
        for (int e = q4*16; e < q4*16 + 16; ++e) {
            float s = 0.f;
            for (int m = 0; m < 64; ++m) s += wb[o*64+m] * g1[m*64+e];
            M2[b*4096 + o*64+e] = s;
        }
    }
}

// ---------------------------------------------------------------------------
// Small weight-folding products:
//  0: Wtr = rq^T rk   1: Wtc = cq^T ck
//  2: Wf2p = gr * Wf[:,64:128] @ rv   3: Wf3p = gc * Wf[:,128:192] @ cv
//  4: Wfx  = Wf[:,64:128] + Wf[:,128:192]
// ---------------------------------------------------------------------------
__global__ __launch_bounds__(256) void k_small_mats(
    const float* __restrict__ rq, const float* __restrict__ rk,
    const float* __restrict__ cq, const float* __restrict__ ck,
    const float* __restrict__ fw, const float* __restrict__ rv,
    const float* __restrict__ cv, const float* __restrict__ rg,
    const float* __restrict__ cg,
    float* __restrict__ Wtr, float* __restrict__ Wtc,
    float* __restrict__ Wf2p, float* __restrict__ Wf3p,
    float* __restrict__ Wfx)
{
    const int which = blockIdx.x, t = threadIdx.x;
    const int a = t >> 2, b0 = (t & 3) * 16;
    if (which <= 1) {
        const float* Q = which ? cq : rq;
        const float* Kw = which ? ck : rk;
        float* O = which ? Wtc : Wtr;
        for (int b = b0; b < b0 + 16; ++b) {
            float s = 0.f;
            for (int co = 0; co < 64; ++co) s += Q[co*64 + a] * Kw[co*64 + b];
            O[a*64 + b] = s;
        }
    } else if (which <= 3) {
        const float* Vw = (which == 2) ? rv : cv;
        const float g = (which == 2) ? rg[0] : cg[0];
        const int off = (which == 2) ? 64 : 128;
        float* O = (which == 2) ? Wf2p : Wf3p;
        for (int b = b0; b < b0 + 16; ++b) {
            float s = 0.f;
            for (int m = 0; m < 64; ++m) s += fw[a*192 + off + m] * Vw[m*64 + b];
            O[a*64 + b] = g * s;
        }
    } else {
        for (int b = b0; b < b0 + 16; ++b)
            Wfx[a*64 + b] = fw[a*192 + 64 + b] + fw[a*192 + 128 + b];
    }
}

// ---------------------------------------------------------------------------
// Fused per-line scores: Y = Wt @ X computed in LDS, then
// P[i][j] = softmax_j( sum_c X[c][i] * Y[c][j] ).
// grid (192, B), block = 256 (16x16 grid, 12x12 register tile).
// dyn LDS = (2*64*196 + 64*68)*4 = 117760 B -> 1 block/CU.
// ---------------------------------------------------------------------------
#define SP 196
__global__ __launch_bounds__(256, 1) void k_attn_sf(
    const float* __restrict__ X, const float* __restrict__ Wt,
    float* __restrict__ P)
{
    extern __shared__ float sm[];
    float* Xl = sm;                    // [64][196]
    float* Yl = sm + 64*SP;            // [64][196]
    float* Wl = sm + 2*64*SP;          // [64][68]  Wl[b][a] = Wt[a][b]
    float* red  = sm;                  // overlay on Xl after S compute
    float* mrow = sm + 192*17;         // 192
    float* lrow = sm + 192*17 + 192;   // 192
    const int t = threadIdx.x;
    const int h = blockIdx.x, b = blockIdx.y;
    const size_t gbase = (size_t)b*(C*NPIX) + (size_t)h*WW;
#pragma unroll 4
    for (int k = 0; k < 48; ++k) {
        const int idx = k*256 + t;
        const int c = idx / 192, j = idx - c*192;
        Xl[c*SP + j] = X[gbase + (size_t)c*NPIX + j];
    }
#pragma unroll
    for (int k = 0; k < 16; ++k) {
        const int idx = k*256 + t;                 // idx = a*64 + b2
        Wl[(idx & 63)*68 + (idx >> 6)] = Wt[idx];
    }
    __syncthreads();
    // --- Y[c][j] = sum_c2 Wt[c][c2] * X[c2][j] ---
    {
        const int c = t >> 2, j0y = (t & 3) * 48;
        float wreg[64];
#pragma unroll
        for (int c2 = 0; c2 < 64; ++c2) wreg[c2] = Wl[c2*68 + c];
#pragma unroll
        for (int m = 0; m < 12; ++m) {
            float ax = 0.f, ay = 0.f, az = 0.f, aw = 0.f;
#pragma unroll 8
            for (int c2 = 0; c2 < 64; ++c2) {
                const float4 xv = *reinterpret_cast<const float4*>(&Xl[c2*SP + j0y + 4*m]);
                ax += wreg[c2]*xv.x; ay += wreg[c2]*xv.y;
                az += wreg[c2]*xv.z; aw += wreg[c2]*xv.w;
            }
            float4 o; o.x = ax; o.y = ay; o.z = az; o.w = aw;
            *reinterpret_cast<float4*>(&Yl[c*SP + j0y + 4*m]) = o;
        }
    }
    __syncthreads();
    // --- S = X^T Y, 12x12 per thread ---
    const int ti = t & 15, tj = t >> 4;
    const int i0 = ti*12, j0 = tj*12;
    float acc[12][12];
#pragma unroll
    for (int r = 0; r < 12; ++r)
#pragma unroll
        for (int s = 0; s < 12; ++s) acc[r][s] = 0.f;
#pragma unroll 2
    for (int c = 0; c < 64; ++c) {
        const float4 xa = *reinterpret_cast<const float4*>(&Xl[c*SP + i0]);
        const float4 xb = *reinterpret_cast<const float4*>(&Xl[c*SP + i0 + 4]);
        const float4 xc = *reinterpret_cast<const float4*>(&Xl[c*SP + i0 + 8]);
        const float4 ya = *reinterpret_cast<const float4*>(&Yl[c*SP + j0]);
        const float4 yb = *reinterpret_cast<const float4*>(&Yl[c*SP + j0 + 4]);
        const float4 yc = *reinterpret_cast<const float4*>(&Yl[c*SP + j0 + 8]);
        const float xr[12] = {xa.x,xa.y,xa.z,xa.w, xb.x,xb.y,xb.z,xb.w, xc.x,xc.y,xc.z,xc.w};
        const float yr[12] = {ya.x,ya.y,ya.z,ya.w, yb.x,yb.y,yb.z,yb.w, yc.x,yc.y,yc.z,yc.w};
#pragma unroll
        for (int r = 0; r < 12; ++r)
#pragma unroll
            for (int s = 0; s < 12; ++s) acc[r][s] += xr[r] * yr[s];
    }
    __syncthreads();   // done reading Xl/Yl; red overlays Xl
#pragma unroll
    for (int r = 0; r < 12; ++r) {
        float pm = acc[r][0];
#pragma unroll
        for (int s = 1; s < 12; ++s) pm = fmaxf(pm, acc[r][s]);
        red[(i0 + r)*17 + tj] = pm;
    }
    __syncthreads();
    if (t < 192) {
        float m = red[t*17];
#pragma unroll
        for (int k = 1; k < 16; ++k) m = fmaxf(m, red[t*17 + k]);
        mrow[t] = m;
    }
    __syncthreads();
#pragma unroll
    for (int r = 0; r < 12; ++r) {
        const float mi = mrow[i0 + r];
        float ps = 0.f;
#pragma unroll
        for (int s = 0; s < 12; ++s) {
            acc[r][s] = __expf(acc[r][s] - mi);
            ps += acc[r][s];
        }
        red[(i0 + r)*17 + tj] = ps;
    }
    __syncthreads();
    if (t < 192) {
        float l = 0.f;
#pragma unroll
        for (int k = 0; k < 16; ++k) l += red[t*17 + k];
        lrow[t] = 1.f / l;
    }
    __syncthreads();
    float* Pb = P + (size_t)(b*HH + h) * LINE_ELEMS;
#pragma unroll
    for (int r = 0; r < 12; ++r) {
        const float inv = lrow[i0 + r];
        float4 o0, o1, o2;
        o0.x = acc[r][0]*inv;  o0.y = acc[r][1]*inv;  o0.z = acc[r][2]*inv;  o0.w = acc[r][3]*inv;
        o1.x = acc[r][4]*inv;  o1.y = acc[r][5]*inv;  o1.z = acc[r][6]*inv;  o1.w = acc[r][7]*inv;
        o2.x = acc[r][8]*inv;  o2.y = acc[r][9]*inv;  o2.z = acc[r][10]*inv; o2.w = acc[r][11]*inv;
        float* pr = Pb + (size_t)(i0 + r)*192 + j0;
        *reinterpret_cast<float4*>(pr)     = o0;
        *reinterpret_cast<float4*>(pr + 4) = o1;
        *reinterpret_cast<float4*>(pr + 8) = o2;
    }
}

// ---------------------------------------------------------------------------
// Per-line apply: Z[c][i] = sum_j U[c][j] * P[i][j].
// grid (192, B), block = 256 (16 c x 16 i threads, 4x12 tile each).
// j tiled by 48. dyn LDS = (48*196 + 48*68)*4 = 50688 B (3 blocks/CU).
// Z never aliases U in this round's schedule.
// ---------------------------------------------------------------------------
#define PTS 196
#define UTS 68
__global__ __launch_bounds__(256) void k_attn_z(
    const float* __restrict__ U, const float* __restrict__ P,
    float* __restrict__ Z)
{
    extern __shared__ float sm[];
    float* Pt = sm;              // [48][196]
    float* Ut = sm + 48*PTS;     // [48][68]
    const int t = threadIdx.x;
    const int h = blockIdx.x, b = blockIdx.y;
    const size_t ubase = (size_t)b*(C*NPIX) + (size_t)h*WW;
    const float* Pl = P + (size_t)(b*HH + h) * LINE_ELEMS;
    const int ci = t & 15, ii = t >> 4;
    const int c0 = 4*ci, i0 = 12*ii;
    float acc[4][12];
#pragma unroll
    for (int k = 0; k < 4; ++k)
#pragma unroll
        for (int m = 0; m < 12; ++m) acc[k][m] = 0.f;
    for (int jt = 0; jt < 192; jt += 48) {
#pragma unroll 4
        for (int k = 0; k < 36; ++k) {
            const int idx = k*256 + t;
            const int i = idx / 48, j = idx - i*48;
            Pt[j*PTS + i] = Pl[(size_t)i*192 + jt + j];
        }
#pragma unroll 4
        for (int k = 0; k < 12; ++k) {
            const int idx = k*256 + t;
            const int c = idx / 48, j = idx - c*48;
            Ut[j*UTS + c] = U[ubase + (size_t)c*NPIX + jt + j];
        }
        __syncthreads();
#pragma unroll 2
        for (int j = 0; j < 48; ++j) {
            const float4 uf = *reinterpret_cast<const float4*>(&Ut[j*UTS + c0]);
            const float4 p0 = *reinterpret_cast<const float4*>(&Pt[j*PTS + i0]);
            const float4 p1 = *reinterpret_cast<const float4*>(&Pt[j*PTS + i0 + 4]);
            const float4 p2 = *reinterpret_cast<const float4*>(&Pt[j*PTS + i0 + 8]);
            const float ur[4]  = {uf.x, uf.y, uf.z, uf.w};
            const float pr[12] = {p0.x,p0.y,p0.z,p0.w, p1.x,p1.y,p1.z,p1.w, p2.x,p2.y,p2.z,p2.w};
#pragma unroll
            for (int k = 0; k < 4; ++k)
#pragma unroll
                for (int m = 0; m < 12; ++m) acc[k][m] += ur[k] * pr[m];
        }
        __syncthreads();
    }
#pragma unroll
    for (int k = 0; k < 4; ++k) {
        float* zr = Z + ubase + (size_t)(c0 + k)*NPIX + i0;
        float4 o0, o1, o2;
        o0.x = acc[k][0]; o0.y = acc[k][1]; o0.z = acc[k][2];  o0.w = acc[k][3];
        o1.x = acc[k][4]; o1.y = acc[k][5]; o1.z = acc[k][6];  o1.w = acc[k][7];
        o2.x = acc[k][8]; o2.y = acc[k][9]; o2.z = acc[k][10]; o2.w = acc[k][11];
        *reinterpret_cast<float4*>(zr)     = o0;
        *reinterpret_cast<float4*>(zr + 4) = o1;
        *reinterpret_cast<float4*>(zr + 8) = o2;
    }
}

// ---------------------------------------------------------------------------
// HW transpose per image: out[img][x][y] = in[img][y][x]. grid (6,6,B*C).
// ---------------------------------------------------------------------------
__global__ __launch_bounds__(256) void k_transpose(
    const float* __restrict__ in, float* __restrict__ out)
{
    __shared__ float tile[32][33];
    const int tx = threadIdx.x & 31, ty = threadIdx.x >> 5;
    const int x0 = blockIdx.x*32, y0 = blockIdx.y*32;
    const float* img = in + blockIdx.z * NPIX;
    float* og = out + blockIdx.z * NPIX;
#pragma unroll
    for (int r = ty; r < 32; r += 8) tile[r][tx] = img[(y0+r)*WW + x0+tx];
    __syncthreads();
#pragma unroll
    for (int r = ty; r < 32; r += 8) og[(x0+r)*WW + (y0+tx)] = tile[tx][r];
}

// ---------------------------------------------------------------------------
extern "C" void kernel_launch(void* const* d_in, const int* in_sizes, int n_in,
                              void* d_out, int out_size, void* d_ws, size_t ws_size,
                              hipStream_t stream) {
    const float* x       = (const float*)d_in[0];
    const float* pw_w    = (const float*)d_in[1];
    const float* dw_w    = (const float*)d_in[2];
    const float* dw_b    = (const float*)d_in[3];
    const float* conv2_w = (const float*)d_in[4];
    const float* conv2_b = (const float*)d_in[5];
    const float* conv0_w = (const float*)d_in[6];
    const float* conv0_b = (const float*)d_in[7];
    const float* attq    = (const float*)d_in[8];
    const float* attk    = (const float*)d_in[9];
    const float* attv    = (const float*)d_in[10];
    const float* attp    = (const float*)d_in[11];
    const float* temp    = (const float*)d_in[12];
    const float* rq      = (const float*)d_in[13];
    const float* rk      = (const float*)d_in[14];
    const float* rv      = (const float*)d_in[15];
    const float* rg      = (const float*)d_in[16];
    const float* cq      = (const float*)d_in[17];
    const float* ck      = (const float*)d_in[18];
    const float* cv      = (const float*)d_in[19];
    const float* cg      = (const float*)d_in[20];
    const float* fw      = (const float*)d_in[21];
    const float* fb      = (const float*)d_in[22];

    float* ws = (float*)d_ws;
    float* A  = ws;                 // t0 -> x1 (lives to end)
    float* Bf = ws + (size_t)ST;    // g -> out1 (lives to final pass 1)
    float* Cf = ws + 2*(size_t)ST;  // x1t -> Z3t -> Z2
    float* Df = ws + 3*(size_t)ST;  // out1t -> Z3
    float* Sbuf = ws + 4*(size_t)ST;               // 28.3M floats (P scores)
    float* partials = Sbuf;                        // overlay (dead before Sbuf)
    float* tmpf = Sbuf;                            // overlay (final pass 1 out)
    float* G1 = Sbuf + (size_t)BB*HH*LINE_ELEMS;   // 16384
    float* M2 = G1 + 16384;                        // 16384
    float* Wtr  = M2 + 16384;                      // 5 x 4096
    float* Wtc  = Wtr + 4096;
    float* Wf2p = Wtc + 4096;
    float* Wf3p = Wf2p + 4096;
    float* Wfx  = Wf3p + 4096;

    const size_t need = ((size_t)4*ST + (size_t)BB*HH*LINE_ELEMS
                         + 16384 + 16384 + 5*4096) * sizeof(float);
    if (ws_size < need) {
        fprintf(stderr, "kernel_launch: ws_size %zu < needed %zu\n", ws_size, need);
        return;
    }

    (void)hipFuncSetAttribute((const void*)k_gram_part,
        hipFuncAttributeMaxDynamicSharedMemorySize, 69632);
    (void)hipFuncSetAttribute((const void*)k_attn_small,
        hipFuncAttributeMaxDynamicSharedMemorySize, 74240);
    (void)hipFuncSetAttribute((const void*)k_attn_sf,
        hipFuncAttributeMaxDynamicSharedMemorySize, 117760);
    (void)hipFuncSetAttribute((const void*)k_attn_z,
        hipFuncAttributeMaxDynamicSharedMemorySize, 50688);

    const dim3 blk256(256), blk192(192);
    const dim3 gconv(NPIX/256, BB);      // (144, 4)
    const dim3 gline(HH, BB);            // (192, 4)
    const dim3 gtr(6, 6, BB*C);

    // 0) fold weights
    k_small_mats<<<dim3(5), blk256, 0, stream>>>(rq, rk, cq, ck, fw, rv, cv,
                                                 rg, cg, Wtr, Wtc, Wf2p, Wf3p, Wfx);
    // 1) A = pw_w @ x
    k_conv<false,false,false><<<gconv, blk256, 0, stream>>>(
        x, nullptr, pw_w, nullptr, nullptr, nullptr, nullptr, A, 64, 64);
    // 2) B = gelu(dw3x3(A) + dw_b)
    k_dw<<<dim3(HH, BB*C), blk192, 0, stream>>>(A, dw_w, dw_b, Bf);
    // 3) A = x1 = conv2@B + conv2_b + conv0@x + conv0_b  (t0 in A dead; A not read)
    k_conv<true,false,false><<<gconv, blk256, 0, stream>>>(
        Bf, x, conv2_w, conv0_w, conv2_b, conv0_b, nullptr, A, 64, 64);
    // 4) channel attention collapse -> M2
    k_gram_part<<<gconv, blk256, 69632, stream>>>(A, partials);
    k_gram_reduce<<<dim3(64), blk256, 0, stream>>>(partials, G1);
    k_attn_small<<<dim3(BB), blk256, 74240, stream>>>(G1, attq, attk, attv, attp, temp, M2);
    // 5) B = out1 = M2[b] @ x1
    k_conv<false,true,false><<<gconv, blk256, 0, stream>>>(
        A, nullptr, M2, nullptr, nullptr, nullptr, nullptr, Bf, 64, 64);
    // 6) C = x1t, D = out1t
    k_transpose<<<gtr, blk256, 0, stream>>>(A, Cf);
    k_transpose<<<gtr, blk256, 0, stream>>>(Bf, Df);
    // 7) col attention: P = softmax(x1t^T (Wtc x1t)); C = Z3t = out1t . P^T
    k_attn_sf<<<gline, blk256, 117760, stream>>>(Cf, Wtc, Sbuf);
    k_attn_z<<<gline, blk256, 50688, stream>>>(Df, Sbuf, Cf);
    //    D = Z3 = transpose(Z3t)
    k_transpose<<<gtr, blk256, 0, stream>>>(Cf, Df);
    // 8) row attention: P = softmax(x1^T (Wtr x1)); C = Z2 = out1 . P^T
    k_attn_sf<<<gline, blk256, 117760, stream>>>(A, Wtr, Sbuf);
    k_attn_z<<<gline, blk256, 50688, stream>>>(Bf, Sbuf, Cf);
    // 9) final fuse (folded): out = gelu(Wf1@out1 + Wf2p@Z2 + Wf3p@Z3
    //                                     + Wfx@x1 + fb)
    k_conv<true,false,false><<<gconv, blk256, 0, stream>>>(
        Bf, Cf, fw, Wf2p, fb, nullptr, nullptr, tmpf, 192, 64);
    k_conv<true,false,true><<<gconv, blk256, 0, stream>>>(
        Df, A, Wf3p, Wfx, nullptr, nullptr, tmpf, (float*)d_out, 64, 64);
}

// Round 4
// 1161.019 us; speedup vs baseline: 5.1027x; 1.1572x over previous
//
#include <hip/hip_runtime.h>
#include <cstdio>

#define BB 4
#define C 64
#define HH 192
#define WW 192
#define NPIX (HH*WW)            /* 36864 */
#define ST (BB*C*NPIX)          /* 9437184 floats per tensor */

__device__ __forceinline__ float gelu_f(float v) {
    return 0.5f * v * (1.0f + erff(v * 0.70710678118654752440f));
}

// ---------------------------------------------------------------------------
// Generic 1x1 conv over NCHW: out[b,o,n] = W1@in1 (+ W2@in2) (+bias1)(+bias2)
// (+res)(gelu). grid = (NPIX/256, B), block = 256. out1 never aliases inputs.
// ---------------------------------------------------------------------------
template<bool TWO_IN, bool PERB, bool DO_GELU>
__global__ __launch_bounds__(256) void k_conv(
    const float* __restrict__ in1, const float* __restrict__ in2,
    const float* __restrict__ W1, const float* __restrict__ W2,
    const float* __restrict__ bias1, const float* __restrict__ bias2,
    const float* __restrict__ res, float* __restrict__ out1,
    int ldw1, int ldw2)
{
    const int n = blockIdx.x * 256 + threadIdx.x;
    const int b = blockIdx.y;
    const int base = b * (C * NPIX) + n;
    float xv[C];
#pragma unroll
    for (int c = 0; c < C; ++c) xv[c] = in1[base + c * NPIX];
    float yv[TWO_IN ? C : 1];
    if (TWO_IN) {
#pragma unroll
        for (int c = 0; c < C; ++c) yv[c] = in2[base + c * NPIX];
    }
    const float* w1 = W1 + (PERB ? b * C * C : 0);
    for (int o = 0; o < C; ++o) {
        const float* wr = w1 + o * ldw1;
        float a0 = 0.f, a1 = 0.f, a2 = 0.f, a3 = 0.f;
#pragma unroll
        for (int c = 0; c < C; c += 4) {
            a0 += wr[c+0] * xv[c+0];
            a1 += wr[c+1] * xv[c+1];
            a2 += wr[c+2] * xv[c+2];
            a3 += wr[c+3] * xv[c+3];
        }
        if (TWO_IN) {
            const float* wr2 = W2 + o * ldw2;
#pragma unroll
            for (int c = 0; c < C; c += 4) {
                a0 += wr2[c+0] * yv[c+0];
                a1 += wr2[c+1] * yv[c+1];
                a2 += wr2[c+2] * yv[c+2];
                a3 += wr2[c+3] * yv[c+3];
            }
        }
        float acc = (a0 + a1) + (a2 + a3);
        if (bias1) acc += bias1[o];
        if (bias2) acc += bias2[o];
        const int ob = base + o * NPIX;
        if (res) acc += res[ob];
        if (DO_GELU) acc = gelu_f(acc);
        out1[ob] = acc;
    }
}

// ---------------------------------------------------------------------------
// Depthwise 3x3 (pad 1) + bias + GELU.  grid = (H, B*C), block = 192 (=W).
// ---------------------------------------------------------------------------
__global__ __launch_bounds__(192) void k_dw(
    const float* __restrict__ t0, const float* __restrict__ w,
    const float* __restrict__ bias, float* __restrict__ g)
{
    const int x = threadIdx.x;
    const int y = blockIdx.x;
    const int bc = blockIdx.y;
    const int c = bc & 63;
    const float* img = t0 + bc * NPIX;
    const float* wc = w + c * 9;
    float acc = bias[c];
#pragma unroll
    for (int dy = -1; dy <= 1; ++dy) {
        const int yy = y + dy;
        if (yy < 0 || yy > 191) continue;
#pragma unroll
        for (int dx = -1; dx <= 1; ++dx) {
            const int xx = x + dx;
            if (xx < 0 || xx > 191) continue;
            acc += img[yy*WW + xx] * wc[(dy+1)*3 + (dx+1)];
        }
    }
    g[bc*NPIX + y*WW + x] = gelu_f(acc);
}

// ---------------------------------------------------------------------------
// Per-batch Gram G1 = X1 * X1^T: partial per 256-pixel chunk.
// ---------------------------------------------------------------------------
__global__ __launch_bounds__(256) void k_gram_part(
    const float* __restrict__ x1p, float* __restrict__ part)
{
    extern __shared__ float lt[];     // [256][68]
    const int chunk = blockIdx.x, b = blockIdx.y, t = threadIdx.x;
    const int gbase = b * (C*NPIX) + chunk * 256;
    for (int idx = t; idx < C*256; idx += 256) {
        const int c = idx >> 8, n = idx & 255;
        lt[n*68 + c] = x1p[gbase + c*NPIX + n];
    }
    __syncthreads();
    const int ti = t & 15, tj = t >> 4;
    float acc[4][4];
#pragma unroll
    for (int r = 0; r < 4; ++r)
#pragma unroll
        for (int s = 0; s < 4; ++s) acc[r][s] = 0.f;
    for (int n = 0; n < 256; ++n) {
        const float4 av = *reinterpret_cast<const float4*>(&lt[n*68 + 4*ti]);
        const float4 bv = *reinterpret_cast<const float4*>(&lt[n*68 + 4*tj]);
        const float ar[4] = {av.x, av.y, av.z, av.w};
        const float br[4] = {bv.x, bv.y, bv.z, bv.w};
#pragma unroll
        for (int r = 0; r < 4; ++r)
#pragma unroll
            for (int s = 0; s < 4; ++s) acc[r][s] += ar[r] * br[s];
    }
    float* pb = part + (b*144 + chunk)*4096;
#pragma unroll
    for (int r = 0; r < 4; ++r)
#pragma unroll
        for (int s = 0; s < 4; ++s) pb[(4*ti+r)*64 + (4*tj+s)] = acc[r][s];
}

__global__ __launch_bounds__(256) void k_gram_reduce(
    const float* __restrict__ part, float* __restrict__ G1)
{
    const int flat = blockIdx.x*256 + threadIdx.x;   // < 16384
    const int b = flat >> 12, ij = flat & 4095;
    float s = 0.f;
    for (int ch = 0; ch < 144; ++ch) s += part[(b*144+ch)*4096 + ij];
    G1[flat] = s;
}

// ---------------------------------------------------------------------------
// Channel-attention collapse: per batch, M2 = Wp * blockdiag(attn) * Wv.
// ---------------------------------------------------------------------------
__global__ __launch_bounds__(256) void k_attn_small(
    const float* __restrict__ G1a, const float* __restrict__ Wq,
    const float* __restrict__ Wk, const float* __restrict__ Wv,
    const float* __restrict__ Wp, const float* __restrict__ temp,
    float* __restrict__ M2)
{
    extern __shared__ float sm[];
    float* g1 = sm;
    float* wa = sm + 4096;
    float* wb = sm + 8192;
    float* u  = sm + 12288;
    float* at = sm + 16384;
    float* nq = sm + 18432;
    float* nk = sm + 18496;
    const int b = blockIdx.x, t = threadIdx.x;
    const float* G = G1a + b*4096;
    for (int i = t; i < 4096; i += 256) { g1[i] = G[i]; wa[i] = Wq[i]; wb[i] = Wk[i]; }
    __syncthreads();
    {
        const int r = t >> 2, q4 = t & 3;
        for (int cc = q4*16; cc < q4*16 + 16; ++cc) {
            float s = 0.f;
            for (int k = 0; k < 64; ++k) s += wa[r*64+k] * g1[k*64+cc];
            u[r*64+cc] = s;
        }
    }
    __syncthreads();
    {
        const int d = t >> 2, kq = t & 3;
        float p = 0.f;
        for (int k = kq*16; k < kq*16 + 16; ++k) {
            float tk = 0.f;
            for (int c2 = 0; c2 < 64; ++c2) tk += g1[k*64+c2] * wb[d*64+c2];
            p += wb[d*64+k] * tk;
        }
        p += __shfl_xor(p, 1);
        p += __shfl_xor(p, 2);
        if (kq == 0) nk[d] = sqrtf(fmaxf(p, 0.f));
    }
    if (t < 64) {
        float s = 0.f;
        for (int c2 = 0; c2 < 64; ++c2) s += u[t*64+c2] * wa[t*64+c2];
        nq[t] = sqrtf(fmaxf(s, 0.f));
    }
    __syncthreads();
    if (t < 64) {
        const int gI = t >> 5;
        const float tg = temp[gI];
        const float dq = fmaxf(nq[t], 1e-12f);
        float row[32];
        float mx = -1e30f;
#pragma unroll
        for (int d2 = 0; d2 < 32; ++d2) {
            const int dd = gI*32 + d2;
            float s = 0.f;
            for (int c2 = 0; c2 < 64; ++c2) s += u[t*64+c2] * wb[dd*64+c2];
            s = s * tg / (dq * fmaxf(nk[dd], 1e-12f));
            row[d2] = s; mx = fmaxf(mx, s);
        }
        float se = 0.f;
#pragma unroll
        for (int d2 = 0; d2 < 32; ++d2) { row[d2] = __expf(row[d2]-mx); se += row[d2]; }
        const float inv = 1.f / se;
#pragma unroll
        for (int d2 = 0; d2 < 32; ++d2) at[t*32+d2] = row[d2]*inv;
    }
    __syncthreads();
    for (int i = t; i < 4096; i += 256) { wa[i] = Wv[i]; wb[i] = Wp[i]; }
    __syncthreads();
    {
        const int m = t >> 2, q4 = t & 3, gI = m >> 5;
        for (int e = q4*16; e < q4*16 + 16; ++e) {
            float s = 0.f;
#pragma unroll
            for (int d2 = 0; d2 < 32; ++d2) s += at[m*32+d2] * wa[(gI*32+d2)*64 + e];
            g1[m*64+e] = s;
        }
    }
    __syncthreads();
    {
        const int o = t >> 2, q4 = t & 3;
        for (int e = q4*16; e < q4*16 + 16; ++e) {
            float s = 0.f;
            for (int m = 0; m < 64; ++m) s += wb[o*64+m] * g1[m*64+e];
            M2[b*4096 + o*64+e] = s;
        }
    }
}

// ---------------------------------------------------------------------------
// Small weight-folding products:
//  0: Wtr = rq^T rk   1: Wtc = cq^T ck
//  2: Wf2p = gr * Wf[:,64:128] @ rv   3: Wf3p = gc * Wf[:,128:192] @ cv
//  4: Wfx  = Wf[:,64:128] + Wf[:,128:192]
// ---------------------------------------------------------------------------
__global__ __launch_bounds__(256) void k_small_mats(
    const float* __restrict__ rq, const float* __restrict__ rk,
    const float* __restrict__ cq, const float* __restrict__ ck,
    const float* __restrict__ fw, const float* __restrict__ rv,
    const float* __restrict__ cv, const float* __restrict__ rg,
    const float* __restrict__ cg,
    float* __restrict__ Wtr, float* __restrict__ Wtc,
    float* __restrict__ Wf2p, float* __restrict__ Wf3p,
    float* __restrict__ Wfx)
{
    const int which = blockIdx.x, t = threadIdx.x;
    const int a = t >> 2, b0 = (t & 3) * 16;
    if (which <= 1) {
        const float* Q = which ? cq : rq;
        const float* Kw = which ? ck : rk;
        float* O = which ? Wtc : Wtr;
        for (int b = b0; b < b0 + 16; ++b) {
            float s = 0.f;
            for (int co = 0; co < 64; ++co) s += Q[co*64 + a] * Kw[co*64 + b];
            O[a*64 + b] = s;
        }
    } else if (which <= 3) {
        const float* Vw = (which == 2) ? rv : cv;
        const float g = (which == 2) ? rg[0] : cg[0];
        const int off = (which == 2) ? 64 : 128;
        float* O = (which == 2) ? Wf2p : Wf3p;
        for (int b = b0; b < b0 + 16; ++b) {
            float s = 0.f;
            for (int m = 0; m < 64; ++m) s += fw[a*192 + off + m] * Vw[m*64 + b];
            O[a*64 + b] = g * s;
        }
    } else {
        for (int b = b0; b < b0 + 16; ++b)
            Wfx[a*64 + b] = fw[a*192 + 64 + b] + fw[a*192 + 128 + b];
    }
}

// ---------------------------------------------------------------------------
// FUSED per-line attention: Y = Wt@X (LDS), S = X^T Y, P = softmax_rows(S)
// kept entirely in LDS, Z[c][i] = sum_j U[c][j] * P[i][j] -> global.
// grid (192, B), block = 256.
// LDS (floats): phase A: Xl[64][196]@0, Yl[64][196]@12544, Wl[64][68]@25088
//               phase B: Pl[192][196]@0 (overlay), Ul[64][36]@37632
// dyn LDS = 39936*4 = 159744 B -> 1 block/CU.
// Z may alias U (all U global reads barrier-precede Z stores), but in the
// current schedule Z never aliases anything.
// ---------------------------------------------------------------------------
#define SP 196
#define US 36
__global__ __launch_bounds__(256, 1) void k_attn_fused(
    const float* __restrict__ X, const float* __restrict__ Wt,
    const float* __restrict__ U, float* __restrict__ Z)
{
    extern __shared__ float sm[];
    float* Xl = sm;                    // [64][196]
    float* Yl = sm + 12544;            // [64][196]
    float* Wl = sm + 25088;            // [64][68]  Wl[c2][c] = Wt[c][c2]
    float* Pl = sm;                    // [192][196] overlay (phase B)
    float* Ul = sm + 37632;            // [64][36]
    float* red  = sm;                  // [192][17] overlay on Xl (softmax)
    float* mrow = sm + 192*17;         // 192
    float* lrow = sm + 192*17 + 192;   // 192
    const int t = threadIdx.x;
    const int h = blockIdx.x, b = blockIdx.y;
    const size_t gbase = (size_t)b*(C*NPIX) + (size_t)h*WW;

    // --- phase 0: load X line + W~ ---
#pragma unroll 4
    for (int k = 0; k < 48; ++k) {
        const int idx = k*256 + t;
        const int c = idx / 192, j = idx - c*192;
        Xl[c*SP + j] = X[gbase + (size_t)c*NPIX + j];
    }
#pragma unroll
    for (int k = 0; k < 16; ++k) {
        const int idx = k*256 + t;                 // idx = a*64 + c2
        Wl[(idx & 63)*68 + (idx >> 6)] = Wt[idx];
    }
    __syncthreads();

    // --- phase 1: Y = Wt @ X, 16x16 thread grid, 4x12 register tiles ---
    {
        const int tc = t & 15, tjy = t >> 4;
        const int c0 = 4*tc, j0y = 12*tjy;
        float accy[4][12];
#pragma unroll
        for (int k = 0; k < 4; ++k)
#pragma unroll
            for (int m = 0; m < 12; ++m) accy[k][m] = 0.f;
        for (int c2 = 0; c2 < 64; ++c2) {
            const float4 w4 = *reinterpret_cast<const float4*>(&Wl[c2*68 + c0]);
            const float4 xa = *reinterpret_cast<const float4*>(&Xl[c2*SP + j0y]);
            const float4 xb = *reinterpret_cast<const float4*>(&Xl[c2*SP + j0y + 4]);
            const float4 xc = *reinterpret_cast<const float4*>(&Xl[c2*SP + j0y + 8]);
            const float wr[4]  = {w4.x, w4.y, w4.z, w4.w};
            const float xr[12] = {xa.x,xa.y,xa.z,xa.w, xb.x,xb.y,xb.z,xb.w,
                                  xc.x,xc.y,xc.z,xc.w};
#pragma unroll
            for (int k = 0; k < 4; ++k)
#pragma unroll
                for (int m = 0; m < 12; ++m) accy[k][m] += wr[k] * xr[m];
        }
#pragma unroll
        for (int k = 0; k < 4; ++k) {
            float4 o0, o1, o2;
            o0.x = accy[k][0]; o0.y = accy[k][1]; o0.z = accy[k][2];  o0.w = accy[k][3];
            o1.x = accy[k][4]; o1.y = accy[k][5]; o1.z = accy[k][6];  o1.w = accy[k][7];
            o2.x = accy[k][8]; o2.y = accy[k][9]; o2.z = accy[k][10]; o2.w = accy[k][11];
            float* yr = &Yl[(c0+k)*SP + j0y];
            *reinterpret_cast<float4*>(yr)     = o0;
            *reinterpret_cast<float4*>(yr + 4) = o1;
            *reinterpret_cast<float4*>(yr + 8) = o2;
        }
    }
    __syncthreads();

    // --- phase 2: S = X^T Y, 12x12 per thread ---
    const int ti = t & 15, tj = t >> 4;
    const int i0 = ti*12, j0 = tj*12;
    float acc[12][12];
#pragma unroll
    for (int r = 0; r < 12; ++r)
#pragma unroll
        for (int s = 0; s < 12; ++s) acc[r][s] = 0.f;
#pragma unroll 2
    for (int c = 0; c < 64; ++c) {
        const float4 xa = *reinterpret_cast<const float4*>(&Xl[c*SP + i0]);
        const float4 xb = *reinterpret_cast<const float4*>(&Xl[c*SP + i0 + 4]);
        const float4 xc = *reinterpret_cast<const float4*>(&Xl[c*SP + i0 + 8]);
        const float4 ya = *reinterpret_cast<const float4*>(&Yl[c*SP + j0]);
        const float4 yb = *reinterpret_cast<const float4*>(&Yl[c*SP + j0 + 4]);
        const float4 yc = *reinterpret_cast<const float4*>(&Yl[c*SP + j0 + 8]);
        const float xr[12] = {xa.x,xa.y,xa.z,xa.w, xb.x,xb.y,xb.z,xb.w, xc.x,xc.y,xc.z,xc.w};
        const float yr[12] = {ya.x,ya.y,ya.z,ya.w, yb.x,yb.y,yb.z,yb.w, yc.x,yc.y,yc.z,yc.w};
#pragma unroll
        for (int r = 0; r < 12; ++r)
#pragma unroll
            for (int s = 0; s < 12; ++s) acc[r][s] += xr[r] * yr[s];
    }
    __syncthreads();   // Xl/Yl dead; red overlays Xl

    // --- phase 3: softmax over rows ---
#pragma unroll
    for (int r = 0; r < 12; ++r) {
        float pm = acc[r][0];
#pragma unroll
        for (int s = 1; s < 12; ++s) pm = fmaxf(pm, acc[r][s]);
        red[(i0 + r)*17 + tj] = pm;
    }
    __syncthreads();
    if (t < 192) {
        float m = red[t*17];
#pragma unroll
        for (int k = 1; k < 16; ++k) m = fmaxf(m, red[t*17 + k]);
        mrow[t] = m;
    }
    __syncthreads();
#pragma unroll
    for (int r = 0; r < 12; ++r) {
        const float mi = mrow[i0 + r];
        float ps = 0.f;
#pragma unroll
        for (int s = 0; s < 12; ++s) {
            acc[r][s] = __expf(acc[r][s] - mi);
            ps += acc[r][s];
        }
        red[(i0 + r)*17 + tj] = ps;
    }
    __syncthreads();
    if (t < 192) {
        float l = 0.f;
#pragma unroll
        for (int k = 0; k < 16; ++k) l += red[t*17 + k];
        lrow[t] = 1.f / l;
    }
    __syncthreads();
    float invl[12];
#pragma unroll
    for (int r = 0; r < 12; ++r) invl[r] = lrow[i0 + r];
    __syncthreads();   // lrow/red read complete; Pl may now overwrite

    // --- phase 4: store normalized P into LDS ---
#pragma unroll
    for (int r = 0; r < 12; ++r) {
        const float inv = invl[r];
        float4 o0, o1, o2;
        o0.x = acc[r][0]*inv;  o0.y = acc[r][1]*inv;  o0.z = acc[r][2]*inv;  o0.w = acc[r][3]*inv;
        o1.x = acc[r][4]*inv;  o1.y = acc[r][5]*inv;  o1.z = acc[r][6]*inv;  o1.w = acc[r][7]*inv;
        o2.x = acc[r][8]*inv;  o2.y = acc[r][9]*inv;  o2.z = acc[r][10]*inv; o2.w = acc[r][11]*inv;
        float* pr = &Pl[(i0 + r)*SP + j0];
        *reinterpret_cast<float4*>(pr)     = o0;
        *reinterpret_cast<float4*>(pr + 4) = o1;
        *reinterpret_cast<float4*>(pr + 8) = o2;
    }
    __syncthreads();

    // --- phase 5: Z[c][i] = sum_j U[c][j] * P[i][j], j tiled by 32 ---
    const int ci = t & 15, ii = t >> 4;
    const int c0z = 4*ci, i0z = 12*ii;
    float accz[4][12];
#pragma unroll
    for (int k = 0; k < 4; ++k)
#pragma unroll
        for (int m = 0; m < 12; ++m) accz[k][m] = 0.f;
    for (int jt = 0; jt < 192; jt += 32) {
#pragma unroll
        for (int k = 0; k < 8; ++k) {       // 64*32/256
            const int idx = k*256 + t;
            const int c = idx >> 5, j = idx & 31;
            Ul[c*US + j] = U[gbase + (size_t)c*NPIX + jt + j];
        }
        __syncthreads();
#pragma unroll 2
        for (int jq = 0; jq < 8; ++jq) {
            float4 u4[4], p4[12];
#pragma unroll
            for (int k = 0; k < 4; ++k)
                u4[k] = *reinterpret_cast<const float4*>(&Ul[(c0z+k)*US + 4*jq]);
#pragma unroll
            for (int m = 0; m < 12; ++m)
                p4[m] = *reinterpret_cast<const float4*>(&Pl[(i0z+m)*SP + jt + 4*jq]);
#pragma unroll
            for (int k = 0; k < 4; ++k)
#pragma unroll
                for (int m = 0; m < 12; ++m) {
                    accz[k][m] += u4[k].x * p4[m].x + u4[k].y * p4[m].y
                                + u4[k].z * p4[m].z + u4[k].w * p4[m].w;
                }
        }
        __syncthreads();
    }
#pragma unroll
    for (int k = 0; k < 4; ++k) {
        float* zr = Z + gbase + (size_t)(c0z + k)*NPIX + i0z;
        float4 o0, o1, o2;
        o0.x = accz[k][0]; o0.y = accz[k][1]; o0.z = accz[k][2];  o0.w = accz[k][3];
        o1.x = accz[k][4]; o1.y = accz[k][5]; o1.z = accz[k][6];  o1.w = accz[k][7];
        o2.x = accz[k][8]; o2.y = accz[k][9]; o2.z = accz[k][10]; o2.w = accz[k][11];
        *reinterpret_cast<float4*>(zr)     = o0;
        *reinterpret_cast<float4*>(zr + 4) = o1;
        *reinterpret_cast<float4*>(zr + 8) = o2;
    }
}

// ---------------------------------------------------------------------------
// HW transpose per image: out[img][x][y] = in[img][y][x]. grid (6,6,B*C).
// ---------------------------------------------------------------------------
__global__ __launch_bounds__(256) void k_transpose(
    const float* __restrict__ in, float* __restrict__ out)
{
    __shared__ float tile[32][33];
    const int tx = threadIdx.x & 31, ty = threadIdx.x >> 5;
    const int x0 = blockIdx.x*32, y0 = blockIdx.y*32;
    const float* img = in + blockIdx.z * NPIX;
    float* og = out + blockIdx.z * NPIX;
#pragma unroll
    for (int r = ty; r < 32; r += 8) tile[r][tx] = img[(y0+r)*WW + x0+tx];
    __syncthreads();
#pragma unroll
    for (int r = ty; r < 32; r += 8) og[(x0+r)*WW + (y0+tx)] = tile[tx][r];
}

// ---------------------------------------------------------------------------
extern "C" void kernel_launch(void* const* d_in, const int* in_sizes, int n_in,
                              void* d_out, int out_size, void* d_ws, size_t ws_size,
                              hipStream_t stream) {
    const float* x       = (const float*)d_in[0];
    const float* pw_w    = (const float*)d_in[1];
    const float* dw_w    = (const float*)d_in[2];
    const float* dw_b    = (const float*)d_in[3];
    const float* conv2_w = (const float*)d_in[4];
    const float* conv2_b = (const float*)d_in[5];
    const float* conv0_w = (const float*)d_in[6];
    const float* conv0_b = (const float*)d_in[7];
    const float* attq    = (const float*)d_in[8];
    const float* attk    = (const float*)d_in[9];
    const float* attv    = (const float*)d_in[10];
    const float* attp    = (const float*)d_in[11];
    const float* temp    = (const float*)d_in[12];
    const float* rq      = (const float*)d_in[13];
    const float* rk      = (const float*)d_in[14];
    const float* rv      = (const float*)d_in[15];
    const float* rg      = (const float*)d_in[16];
    const float* cq      = (const float*)d_in[17];
    const float* ck      = (const float*)d_in[18];
    const float* cv      = (const float*)d_in[19];
    const float* cg      = (const float*)d_in[20];
    const float* fw      = (const float*)d_in[21];
    const float* fb      = (const float*)d_in[22];

    float* ws = (float*)d_ws;
    float* A  = ws;                 // t0 -> x1 (lives to end)
    float* Bf = ws + (size_t)ST;    // g -> out1
    float* Cf = ws + 2*(size_t)ST;  // x1t -> Z2
    float* Df = ws + 3*(size_t)ST;  // out1t -> Z3
    float* Ef = ws + 4*(size_t)ST;  // Z3t -> final pass-1 tmp
    float* partials = ws + 5*(size_t)ST;   // 576*4096 = 2359296 floats
    float* G1 = partials + 576*4096;       // 16384
    float* M2 = G1 + 16384;                // 16384
    float* Wtr  = M2 + 16384;              // 5 x 4096
    float* Wtc  = Wtr + 4096;
    float* Wf2p = Wtc + 4096;
    float* Wf3p = Wf2p + 4096;
    float* Wfx  = Wf3p + 4096;

    const size_t need = ((size_t)5*ST + 576*4096 + 16384 + 16384 + 5*4096)
                        * sizeof(float);
    if (ws_size < need) {
        fprintf(stderr, "kernel_launch: ws_size %zu < needed %zu\n", ws_size, need);
        return;
    }

    (void)hipFuncSetAttribute((const void*)k_gram_part,
        hipFuncAttributeMaxDynamicSharedMemorySize, 69632);
    (void)hipFuncSetAttribute((const void*)k_attn_small,
        hipFuncAttributeMaxDynamicSharedMemorySize, 74240);
    (void)hipFuncSetAttribute((const void*)k_attn_fused,
        hipFuncAttributeMaxDynamicSharedMemorySize, 159744);

    const dim3 blk256(256), blk192(192);
    const dim3 gconv(NPIX/256, BB);      // (144, 4)
    const dim3 gline(HH, BB);            // (192, 4)
    const dim3 gtr(6, 6, BB*C);

    // 0) fold weights
    k_small_mats<<<dim3(5), blk256, 0, stream>>>(rq, rk, cq, ck, fw, rv, cv,
                                                 rg, cg, Wtr, Wtc, Wf2p, Wf3p, Wfx);
    // 1) A = pw_w @ x
    k_conv<false,false,false><<<gconv, blk256, 0, stream>>>(
        x, nullptr, pw_w, nullptr, nullptr, nullptr, nullptr, A, 64, 64);
    // 2) B = gelu(dw3x3(A) + dw_b)
    k_dw<<<dim3(HH, BB*C), blk192, 0, stream>>>(A, dw_w, dw_b, Bf);
    // 3) A = x1 = conv2@B + conv0@x + conv2_b + conv0_b
    k_conv<true,false,false><<<gconv, blk256, 0, stream>>>(
        Bf, x, conv2_w, conv0_w, conv2_b, conv0_b, nullptr, A, 64, 64);
    // 4) channel attention collapse -> M2
    k_gram_part<<<gconv, blk256, 69632, stream>>>(A, partials);
    k_gram_reduce<<<dim3(64), blk256, 0, stream>>>(partials, G1);
    k_attn_small<<<dim3(BB), blk256, 74240, stream>>>(G1, attq, attk, attv, attp, temp, M2);
    // 5) B = out1 = M2[b] @ x1
    k_conv<false,true,false><<<gconv, blk256, 0, stream>>>(
        A, nullptr, M2, nullptr, nullptr, nullptr, nullptr, Bf, 64, 64);
    // 6) C = x1t, D = out1t
    k_transpose<<<gtr, blk256, 0, stream>>>(A, Cf);
    k_transpose<<<gtr, blk256, 0, stream>>>(Bf, Df);
    // 7) col attention fused: E = Z3t
    k_attn_fused<<<gline, blk256, 159744, stream>>>(Cf, Wtc, Df, Ef);
    // 8) D = Z3 = transpose(Z3t)
    k_transpose<<<gtr, blk256, 0, stream>>>(Ef, Df);
    // 9) row attention fused: C = Z2
    k_attn_fused<<<gline, blk256, 159744, stream>>>(A, Wtr, Bf, Cf);
    // 10) final fuse (folded): out = gelu(Wf1@out1 + Wf2p@Z2 + Wf3p@Z3
    //                                      + Wfx@x1 + fb)
    k_conv<true,false,false><<<gconv, blk256, 0, stream>>>(
        Bf, Cf, fw, Wf2p, fb, nullptr, nullptr, Ef, 192, 64);
    k_conv<true,false,true><<<gconv, blk256, 0, stream>>>(
        Df, A, Wf3p, Wfx, nullptr, nullptr, Ef, (float*)d_out, 64, 64);
}